// Round 19
// baseline (155.019 us; speedup 1.0000x reference)
//
#include <hip/hip_runtime.h>
#include <math.h>

#define NPTS 32768
#define CAPP 192
#define CAPC 57
#define SLOT 16          // bins2 slots per (tile, block)
#define SCALE ((float)(256.0 / (2.0 * M_PI)))
#define RPT 9

typedef __attribute__((ext_vector_type(8))) short short8b;   // 8 bf16
typedef __attribute__((ext_vector_type(4))) float f32x4;

static __device__ __forceinline__ unsigned short f2bf(float x) {
    unsigned u = __float_as_uint(x);
    return (unsigned short)((u + 0x7fffu + ((u >> 16) & 1u)) >> 16);
}

static __device__ __forceinline__ float bessel_i0f(float x) {
    float hx2 = 0.25f * x * x;
    float t = 1.0f, s = 1.0f;
#pragma unroll
    for (int m = 1; m <= 30; ++m) { t *= hx2 * (1.0f / ((float)m * (float)m)); s += t; }
    return s;
}

// ---------- K1: fused front end, 256 blocks (verbatim R18) ----------
__global__ __launch_bounds__(256) void k_front(
        const float* __restrict__ coords, const float* __restrict__ values,
        unsigned short* __restrict__ Sfrag, float* __restrict__ wxy,
        unsigned* __restrict__ cnts32, unsigned* __restrict__ bins2,
        float* __restrict__ vt) {
    __shared__ unsigned cnt[1024];                  // prep role
    __shared__ float tile[32][257];                 // transpose role
    __shared__ float axf[128];
    __shared__ float2 sSh[256];
    int blk = blockIdx.x;
    int t = threadIdx.x;

    if (blk < 128) {
        // ---- prep ----
        for (int i = t; i < 1024; i += 256) cnt[i] = 0u;
        __syncthreads();
        int k = blk * 256 + t;
        const float inv_i0a = 1.0f / bessel_i0f(14.04f);  // constant-folds
        float2 cv = *(const float2*)&coords[2 * k];
        float gmx = cv.x * SCALE;
        float gmy = cv.y * SCALE;
        float bxf = floorf(gmx - 3.0f), byf = floorf(gmy - 3.0f);
        float wl[12];
#pragma unroll
        for (int j = 0; j < 6; ++j) {
            float ux = gmx - (bxf + (float)(j + 1));
            float rx = ux * (1.0f / 3.0f);
            float argx = 1.0f - rx * rx;
            wl[j] = (argx > 0.0f) ? bessel_i0f(14.04f * sqrtf(argx)) * inv_i0a : 0.0f;
            float uy = gmy - (byf + (float)(j + 1));
            float ry = uy * (1.0f / 3.0f);
            float argy = 1.0f - ry * ry;
            wl[6 + j] = (argy > 0.0f) ? bessel_i0f(14.04f * sqrtf(argy)) * inv_i0a : 0.0f;
        }
        float4* wp = (float4*)&wxy[k * 12];
        wp[0] = *(const float4*)&wl[0];
        wp[1] = *(const float4*)&wl[4];
        wp[2] = *(const float4*)&wl[8];
        int x0 = (((int)bxf) + 1 + 512) & 255;
        int y0 = (((int)byf) + 1 + 512) & 255;
        int tx0 = x0 >> 3, tx1 = ((x0 + 5) & 255) >> 3;
        int ty0 = y0 >> 3, ty1 = ((y0 + 5) & 255) >> 3;
        int nx = (tx1 == tx0) ? 1 : 2;
        int ny = (ty1 == ty0) ? 1 : 2;
        int txs[2] = {tx0, tx1}, tys[2] = {ty0, ty1};
        for (int i = 0; i < nx; ++i)
            for (int j = 0; j < ny; ++j) {
                int tl = txs[i] * 32 + tys[j];
                unsigned ex = (unsigned)((x0 - 8 * txs[i] + 256) & 255);
                unsigned ey = (unsigned)((y0 - 8 * tys[j] + 256) & 255);
                unsigned pos = atomicAdd(&cnt[tl], 1u);      // LDS atomic
                if (pos < SLOT)
                    bins2[(tl * 128 + blk) * SLOT + pos] = ((unsigned)k << 16) | (ex << 8) | ey;
            }
        __syncthreads();
        unsigned c0 = cnt[4 * t],     c1 = cnt[4 * t + 1];
        unsigned c2 = cnt[4 * t + 2], c3 = cnt[4 * t + 3];
        c0 = c0 > SLOT ? SLOT : c0;  c1 = c1 > SLOT ? SLOT : c1;
        c2 = c2 > SLOT ? SLOT : c2;  c3 = c3 > SLOT ? SLOT : c3;
        cnts32[blk * 256 + t] = c0 | (c1 << 8) | (c2 << 16) | (c3 << 24);
    } else {
        // ---- transpose ----
        int kbase = (blk - 128) * 256;
        for (int img = 0; img < 32; ++img)
            tile[img][t] = values[img * NPTS + kbase + t];
        __syncthreads();
        int img = t & 31;
        int k0 = t >> 5;
        for (int r = 0; r < 32; ++r) {
            int kl = k0 + r * 8;
            vt[(kbase + kl) * 32 + img] = tile[img][kl];
        }
        // ---- setup slice (blocks 128..135) ----
        int s = blk - 128;
        if (s < 8) {
            if (t < 128) {
                const float inv_i0a = 1.0f / bessel_i0f(14.04f);
                float om = ((float)t - 63.5f) * (1.0f / 256.0f);
                float pj = (float)M_PI * 6.0f * om;
                float tt = sqrtf(14.04f * 14.04f - pj * pj);
                float kbft = 6.0f * (sinhf(tt) / tt) * inv_i0a;
                axf[t] = 1.0f / kbft;
            }
            __syncthreads();
            float sw, cw;
            __sincosf((float)t * (float)(2.0 * M_PI / 256.0), &sw, &cw);
            float zr = 1.0f, zi = 0.0f, re = 0.0f, im = 0.0f;
            for (int x = 0; x < 128; ++x) {
                float a = axf[x];
                re = fmaf(a, zr, re);
                im = fmaf(a, zi, im);
                float nzr = zr * cw - zi * sw;
                zi = fmaf(zr, sw, zi * cw);
                zr = nzr;
            }
            sSh[t] = make_float2(re, im);
            __syncthreads();
            for (int idx = s * 4096 + t; idx < (s + 1) * 4096; idx += 256) {
                int i   = idx & 7;
                int ln  = (idx >> 3) & 63;
                int ks  = (idx >> 9) & 7;
                int tl  = idx >> 12;
                int si = (32 * ks + 8 * (ln >> 4) + i - 2 * (16 * tl + (ln & 15))) & 255;
                float2 sv = sSh[si];
                Sfrag[idx]         = f2bf(sv.x);
                Sfrag[32768 + idx] = f2bf(sv.y);
                Sfrag[65536 + idx] = f2bf(-sv.y);
            }
        }
    }
}

// ---------- K2: tile gather x RPT (diagnostic inflation, rz=0) ----------
__global__ __launch_bounds__(256) void k_gather_tile(
        const float* __restrict__ wxy, const float* __restrict__ vt,
        const unsigned* __restrict__ cnts32, const unsigned* __restrict__ bins2,
        unsigned short* __restrict__ Gt, int rz) {
    __shared__ unsigned np;
    __shared__ unsigned cnt[64];
    __shared__ unsigned lists[64 * CAPC];
    __shared__ unsigned bsh[CAPP];
    __shared__ unsigned short gsh[64][40];
    int tile = blockIdx.x;
    int TX = tile >> 5, TY = tile & 31;
    int t = threadIdx.x;
    for (int r = 0; r < RPT; ++r) {
        __syncthreads();                    // protect LDS reuse across repeats
        if (t == 0) np = 0u;
        if (t < 64) cnt[t] = 0u;
        __syncthreads();
        // stage 0: compact this tile's entries from 128 per-block groups
        if (t < 128) {
            unsigned word = cnts32[t * 256 + (tile >> 2) + rz * r];
            unsigned cb = (word >> ((tile & 3) * 8)) & 0xFFu;
            if (cb) {
                unsigned pos = atomicAdd(&np, cb);
                const unsigned* src = &bins2[(tile * 128 + t) * SLOT + rz * r];
                for (unsigned e = 0; e < cb; ++e)
                    if (pos + e < CAPP) bsh[pos + e] = src[e];
            }
        }
        __syncthreads();
        unsigned n = np;
        if (n > CAPP) n = CAPP;
        // stage A: build per-cell entry lists
        int total = (int)n * 6;
        for (int task = t; task < total; task += 256) {
            int pi = task / 6;
            int jx = task - pi * 6;
            unsigned en = bsh[pi];
            int ex = (int)((en >> 8) & 255u);
            int ey = (int)(en & 255u);
            if (((ex + jx) & 255) < 8) {
                unsigned k = en >> 16;
                float wxv = wxy[k * 12 + jx];
                int lx = ((ex + jx) & 7) << 3;
                unsigned kq = k << 16;
                int jy0, jy1;
                if (ey <= 7) { jy0 = 0; jy1 = (7 - ey < 5) ? 7 - ey : 5; }
                else         { jy0 = 256 - ey; jy1 = 5; }
                for (int jy = jy0; jy <= jy1; ++jy) {
                    float w = wxv * wxy[k * 12 + 6 + jy];
                    unsigned q = (unsigned)(w * 65535.0f + 0.5f);
                    if (q > 65535u) q = 65535u;
                    int cl = lx | ((ey + jy) & 7);
                    unsigned pos = atomicAdd(&cnt[cl], 1u);
                    if (pos < CAPC) lists[cl * CAPC + pos] = kq | q;
                }
            }
        }
        __syncthreads();
        // stage B: thread owns (cell c, 8 images); register gather
        int c = t >> 2;
        int ib = (t & 3) * 8;
        unsigned nc = cnt[c];
        if (nc > CAPC) nc = CAPC;
        float acc0 = 0, acc1 = 0, acc2 = 0, acc3 = 0, acc4 = 0, acc5 = 0, acc6 = 0, acc7 = 0;
        for (unsigned e = 0; e < nc; ++e) {
            unsigned en = lists[c * CAPC + e];
            float w = (float)(en & 0xFFFFu) * (1.0f / 65535.0f);
            const float* vp = &vt[(en >> 16) * 32 + ib];
            float4 va = *(const float4*)vp;
            float4 vb = *(const float4*)(vp + 4);
            acc0 += w * va.x; acc1 += w * va.y; acc2 += w * va.z; acc3 += w * va.w;
            acc4 += w * vb.x; acc5 += w * vb.y; acc6 += w * vb.z; acc7 += w * vb.w;
        }
        {
            unsigned short* gp = &gsh[c][ib];
            gp[0] = f2bf(acc0); gp[1] = f2bf(acc1); gp[2] = f2bf(acc2); gp[3] = f2bf(acc3);
            gp[4] = f2bf(acc4); gp[5] = f2bf(acc5); gp[6] = f2bf(acc6); gp[7] = f2bf(acc7);
        }
        __syncthreads();
        // writeout
        {
            int img = t >> 3;
            int vr = t & 7;
            short8b row;
#pragma unroll
            for (int uu = 0; uu < 8; ++uu)
                row[uu] = (short)gsh[(uu << 3) | vr][img];
            *(short8b*)&Gt[img * 65536 + (((TY << 3) + vr) << 8) + (TX << 3) + rz * r] = row;
        }
    }
}

// ---------- K3: MFMA spectral stage (verbatim R18) ----------
__global__ __launch_bounds__(512) void k_mmx(const unsigned short* __restrict__ Gt,
                                             const unsigned short* __restrict__ Sfrag,
                                             float* __restrict__ out) {
    __shared__ unsigned short T1[2][16][264];
    int blk = blockIdx.x;
    int band = blk >> 5;
    int img = blk & 31;
    int t = threadIdx.x;
    int lane = t & 63;
    int w = t >> 6;
    int g4 = lane >> 4;
    int l15 = lane & 15;

    {
        int var = w >> 2;
        const unsigned short* sf = Sfrag + var * 32768 + band * 4096 + lane * 8;
        short8b a[8];
#pragma unroll
        for (int ks = 0; ks < 8; ++ks)
            a[ks] = *(const short8b*)(sf + ks * 512);
        const unsigned short* gimg = Gt + img * 65536 + 8 * g4;
#pragma unroll
        for (int j = 0; j < 4; ++j) {
            int vtile = (w & 3) + j * 4;
            int v0 = vtile * 16;
            const unsigned short* gb = gimg + (v0 + l15) * 256;
            f32x4 acc = {0.f, 0.f, 0.f, 0.f};
#pragma unroll
            for (int ks = 0; ks < 8; ++ks) {
                short8b b = *(const short8b*)(gb + ks * 32);
                acc = __builtin_amdgcn_mfma_f32_16x16x32_bf16(a[ks], b, acc, 0, 0, 0);
            }
            int vcol = v0 + l15;
#pragma unroll
            for (int r = 0; r < 4; ++r) {
                int p = g4 * 4 + r;
                T1[var][p][vcol ^ ((p & 7) << 3)] = f2bf(acc[r]);
            }
        }
    }
    __syncthreads();

    {
        int qt = w;
        const unsigned short* sfq = Sfrag + qt * 4096 + lane * 8;
        int swz = (l15 & 7) << 3;
        f32x4 accR = {0.f, 0.f, 0.f, 0.f}, accI = {0.f, 0.f, 0.f, 0.f};
#pragma unroll
        for (int ks = 0; ks < 8; ++ks) {
            int vidx = (32 * ks + 8 * g4) ^ swz;
            short8b aR = *(const short8b*)&T1[0][l15][vidx];
            short8b aI = *(const short8b*)&T1[1][l15][vidx];
            short8b bR = *(const short8b*)(sfq + ks * 512);
            short8b bI = *(const short8b*)(sfq + 32768 + ks * 512);
            short8b bN = *(const short8b*)(sfq + 65536 + ks * 512);
            accR = __builtin_amdgcn_mfma_f32_16x16x32_bf16(aR, bR, accR, 0, 0, 0);
            accR = __builtin_amdgcn_mfma_f32_16x16x32_bf16(aI, bN, accR, 0, 0, 0);
            accI = __builtin_amdgcn_mfma_f32_16x16x32_bf16(aR, bI, accI, 0, 0, 0);
            accI = __builtin_amdgcn_mfma_f32_16x16x32_bf16(aI, bR, accI, 0, 0, 0);
        }
        int q = qt * 16 + l15;
        int b_ = img >> 2, c_ = img & 3;
        int obase = ((b_ ^ 4) * 4 + (c_ ^ 2)) * 128;
#pragma unroll
        for (int r = 0; r < 4; ++r) {
            int p = band * 16 + g4 * 4 + r;
            float re = accR[r], im = accI[r];
            out[((obase + (p ^ 64)) << 7) + (q ^ 64)] = sqrtf(re * re + im * im);
        }
    }
}

extern "C" void kernel_launch(void* const* d_in, const int* in_sizes, int n_in,
                              void* d_out, int out_size, void* d_ws, size_t ws_size,
                              hipStream_t stream) {
    const float* values = (const float*)d_in[0];   // [8,4,32768] f32
    const float* coords = (const float*)d_in[1];   // [32768,2] f32

    char* ws = (char*)d_ws;
    unsigned short* Sfrag = (unsigned short*)(ws + 0);          // 192 KB
    float*    wxy         = (float*)(ws + 262144);              // 1.5 MB [32768*12]
    unsigned* cnts32      = (unsigned*)(ws + 1835008);          // 128 KB [128][256] packed u8x4
    unsigned* bins2       = (unsigned*)(ws + 1966080);          // 8 MB  [1024][128][SLOT]
    unsigned short* Gt    = (unsigned short*)(ws + 10354688);   // 4 MB  [32][256v][256u] bf16
    float*    vt          = (float*)(ws + 14548992);            // 4 MB  [32768][32]

    k_front<<<256, 256, 0, stream>>>(coords, values, Sfrag, wxy, cnts32, bins2, vt);
    k_gather_tile<<<1024, 256, 0, stream>>>(wxy, vt, cnts32, bins2, Gt, 0);
    k_mmx<<<256, 512, 0, stream>>>(Gt, Sfrag, (float*)d_out);
}

// Round 20
// 45.086 us; speedup vs baseline: 3.4383x; 3.4383x over previous
//
#include <hip/hip_runtime.h>
#include <math.h>

#define NPTS 32768
#define CAPP 192
#define CAPC 57
#define SLOT 16          // bins2 slots per (tile, block)
#define SCALE ((float)(256.0 / (2.0 * M_PI)))

typedef __attribute__((ext_vector_type(8))) short short8b;   // 8 bf16
typedef __attribute__((ext_vector_type(4))) float f32x4;

static __device__ __forceinline__ unsigned short f2bf(float x) {
    unsigned u = __float_as_uint(x);
    return (unsigned short)((u + 0x7fffu + ((u >> 16) & 1u)) >> 16);
}

static __device__ __forceinline__ float bessel_i0f(float x) {
    float hx2 = 0.25f * x * x;
    float t = 1.0f, s = 1.0f;
#pragma unroll
    for (int m = 1; m <= 30; ++m) { t *= hx2 * (1.0f / ((float)m * (float)m)); s += t; }
    return s;
}

// ---------- K1: fused front end, 256 blocks (verbatim R18) ----------
__global__ __launch_bounds__(256) void k_front(
        const float* __restrict__ coords, const float* __restrict__ values,
        unsigned short* __restrict__ Sfrag, float* __restrict__ wxy,
        unsigned* __restrict__ cnts32, unsigned* __restrict__ bins2,
        float* __restrict__ vt) {
    __shared__ unsigned cnt[1024];                  // prep role
    __shared__ float tile[32][257];                 // transpose role
    __shared__ float axf[128];
    __shared__ float2 sSh[256];
    int blk = blockIdx.x;
    int t = threadIdx.x;

    if (blk < 128) {
        // ---- prep ----
        for (int i = t; i < 1024; i += 256) cnt[i] = 0u;
        __syncthreads();
        int k = blk * 256 + t;
        const float inv_i0a = 1.0f / bessel_i0f(14.04f);  // constant-folds
        float2 cv = *(const float2*)&coords[2 * k];
        float gmx = cv.x * SCALE;
        float gmy = cv.y * SCALE;
        float bxf = floorf(gmx - 3.0f), byf = floorf(gmy - 3.0f);
        float wl[12];
#pragma unroll
        for (int j = 0; j < 6; ++j) {
            float ux = gmx - (bxf + (float)(j + 1));
            float rx = ux * (1.0f / 3.0f);
            float argx = 1.0f - rx * rx;
            wl[j] = (argx > 0.0f) ? bessel_i0f(14.04f * sqrtf(argx)) * inv_i0a : 0.0f;
            float uy = gmy - (byf + (float)(j + 1));
            float ry = uy * (1.0f / 3.0f);
            float argy = 1.0f - ry * ry;
            wl[6 + j] = (argy > 0.0f) ? bessel_i0f(14.04f * sqrtf(argy)) * inv_i0a : 0.0f;
        }
        float4* wp = (float4*)&wxy[k * 12];
        wp[0] = *(const float4*)&wl[0];
        wp[1] = *(const float4*)&wl[4];
        wp[2] = *(const float4*)&wl[8];
        int x0 = (((int)bxf) + 1 + 512) & 255;
        int y0 = (((int)byf) + 1 + 512) & 255;
        int tx0 = x0 >> 3, tx1 = ((x0 + 5) & 255) >> 3;
        int ty0 = y0 >> 3, ty1 = ((y0 + 5) & 255) >> 3;
        int nx = (tx1 == tx0) ? 1 : 2;
        int ny = (ty1 == ty0) ? 1 : 2;
        int txs[2] = {tx0, tx1}, tys[2] = {ty0, ty1};
        for (int i = 0; i < nx; ++i)
            for (int j = 0; j < ny; ++j) {
                int tl = txs[i] * 32 + tys[j];
                unsigned ex = (unsigned)((x0 - 8 * txs[i] + 256) & 255);
                unsigned ey = (unsigned)((y0 - 8 * tys[j] + 256) & 255);
                unsigned pos = atomicAdd(&cnt[tl], 1u);      // LDS atomic
                if (pos < SLOT)
                    bins2[(tl * 128 + blk) * SLOT + pos] = ((unsigned)k << 16) | (ex << 8) | ey;
            }
        __syncthreads();
        unsigned c0 = cnt[4 * t],     c1 = cnt[4 * t + 1];
        unsigned c2 = cnt[4 * t + 2], c3 = cnt[4 * t + 3];
        c0 = c0 > SLOT ? SLOT : c0;  c1 = c1 > SLOT ? SLOT : c1;
        c2 = c2 > SLOT ? SLOT : c2;  c3 = c3 > SLOT ? SLOT : c3;
        cnts32[blk * 256 + t] = c0 | (c1 << 8) | (c2 << 16) | (c3 << 24);
    } else {
        // ---- transpose ----
        int kbase = (blk - 128) * 256;
        for (int img = 0; img < 32; ++img)
            tile[img][t] = values[img * NPTS + kbase + t];
        __syncthreads();
        int img = t & 31;
        int k0 = t >> 5;
        for (int r = 0; r < 32; ++r) {
            int kl = k0 + r * 8;
            vt[(kbase + kl) * 32 + img] = tile[img][kl];
        }
        // ---- setup slice (blocks 128..135) ----
        int s = blk - 128;
        if (s < 8) {
            if (t < 128) {
                const float inv_i0a = 1.0f / bessel_i0f(14.04f);
                float om = ((float)t - 63.5f) * (1.0f / 256.0f);
                float pj = (float)M_PI * 6.0f * om;
                float tt = sqrtf(14.04f * 14.04f - pj * pj);
                float kbft = 6.0f * (sinhf(tt) / tt) * inv_i0a;
                axf[t] = 1.0f / kbft;
            }
            __syncthreads();
            float sw, cw;
            __sincosf((float)t * (float)(2.0 * M_PI / 256.0), &sw, &cw);
            float zr = 1.0f, zi = 0.0f, re = 0.0f, im = 0.0f;
            for (int x = 0; x < 128; ++x) {
                float a = axf[x];
                re = fmaf(a, zr, re);
                im = fmaf(a, zi, im);
                float nzr = zr * cw - zi * sw;
                zi = fmaf(zr, sw, zi * cw);
                zr = nzr;
            }
            sSh[t] = make_float2(re, im);
            __syncthreads();
            for (int idx = s * 4096 + t; idx < (s + 1) * 4096; idx += 256) {
                int i   = idx & 7;
                int ln  = (idx >> 3) & 63;
                int ks  = (idx >> 9) & 7;
                int tl  = idx >> 12;
                int si = (32 * ks + 8 * (ln >> 4) + i - 2 * (16 * tl + (ln & 15))) & 255;
                float2 sv = sSh[si];
                Sfrag[idx]         = f2bf(sv.x);
                Sfrag[32768 + idx] = f2bf(sv.y);
                Sfrag[65536 + idx] = f2bf(-sv.y);
            }
        }
    }
}

// ---------- K2: tile gather -> Gt[img][v][u] in bf16 ----------
// stage 0 compacts entries AND stages each point's 12 weights into LDS (wsh);
// stage A is then LDS-only (kills the 1.4M scattered 4B wxy reads).
__global__ __launch_bounds__(256) void k_gather_tile(
        const float* __restrict__ wxy, const float* __restrict__ vt,
        const unsigned* __restrict__ cnts32, const unsigned* __restrict__ bins2,
        unsigned short* __restrict__ Gt) {
    __shared__ unsigned np;
    __shared__ unsigned cnt[64];
    __shared__ unsigned lists[64 * CAPC];   // entry = (pi или k:15 << 16) | (w:16)
    __shared__ unsigned bsh[CAPP];
    __shared__ float wsh[CAPP * 12];        // staged per-point 1D weights (9 KB)
    __shared__ unsigned short gsh[64][40];  // [cell][img] pad 40
    int tile = blockIdx.x;                  // 0..1023
    int TX = tile >> 5, TY = tile & 31;
    int t = threadIdx.x;
    if (t == 0) np = 0u;
    if (t < 64) cnt[t] = 0u;
    __syncthreads();
    // stage 0: compact entries + stage weights
    if (t < 128) {
        unsigned word = cnts32[t * 256 + (tile >> 2)];
        unsigned cb = (word >> ((tile & 3) * 8)) & 0xFFu;
        if (cb) {
            unsigned pos = atomicAdd(&np, cb);
            const unsigned* src = &bins2[(tile * 128 + t) * SLOT];
            for (unsigned e = 0; e < cb; ++e) {
                if (pos + e < CAPP) {
                    unsigned en = src[e];
                    bsh[pos + e] = en;
                    const float4* wp = (const float4*)&wxy[(en >> 16) * 12];
                    float4* wd = (float4*)&wsh[(pos + e) * 12];
                    wd[0] = wp[0];
                    wd[1] = wp[1];
                    wd[2] = wp[2];
                }
            }
        }
    }
    __syncthreads();
    unsigned n = np;
    if (n > CAPP) n = CAPP;
    // stage A: build per-cell entry lists (weights from LDS)
    int total = (int)n * 6;
    for (int task = t; task < total; task += 256) {
        int pi = task / 6;
        int jx = task - pi * 6;
        unsigned en = bsh[pi];
        int ex = (int)((en >> 8) & 255u);
        int ey = (int)(en & 255u);
        if (((ex + jx) & 255) < 8) {
            float wxv = wsh[pi * 12 + jx];
            int lx = ((ex + jx) & 7) << 3;
            unsigned kq = (en >> 16) << 16;
            int jy0, jy1;
            if (ey <= 7) { jy0 = 0; jy1 = (7 - ey < 5) ? 7 - ey : 5; }
            else         { jy0 = 256 - ey; jy1 = 5; }
            for (int jy = jy0; jy <= jy1; ++jy) {
                float w = wxv * wsh[pi * 12 + 6 + jy];
                unsigned q = (unsigned)(w * 65535.0f + 0.5f);
                if (q > 65535u) q = 65535u;
                int cl = lx | ((ey + jy) & 7);
                unsigned pos = atomicAdd(&cnt[cl], 1u);    // native u32 LDS atomic
                if (pos < CAPC) lists[cl * CAPC + pos] = kq | q;
            }
        }
    }
    __syncthreads();
    // stage B: thread owns (cell c, 8 images); pure register gather
    int c = t >> 2;
    int ib = (t & 3) * 8;
    unsigned nc = cnt[c];
    if (nc > CAPC) nc = CAPC;
    float acc0 = 0, acc1 = 0, acc2 = 0, acc3 = 0, acc4 = 0, acc5 = 0, acc6 = 0, acc7 = 0;
    for (unsigned e = 0; e < nc; ++e) {
        unsigned en = lists[c * CAPC + e];             // broadcast within quad
        float w = (float)(en & 0xFFFFu) * (1.0f / 65535.0f);
        const float* vp = &vt[(en >> 16) * 32 + ib];
        float4 va = *(const float4*)vp;
        float4 vb = *(const float4*)(vp + 4);
        acc0 += w * va.x; acc1 += w * va.y; acc2 += w * va.z; acc3 += w * va.w;
        acc4 += w * vb.x; acc5 += w * vb.y; acc6 += w * vb.z; acc7 += w * vb.w;
    }
    {
        unsigned short* gp = &gsh[c][ib];
        gp[0] = f2bf(acc0); gp[1] = f2bf(acc1); gp[2] = f2bf(acc2); gp[3] = f2bf(acc3);
        gp[4] = f2bf(acc4); gp[5] = f2bf(acc5); gp[6] = f2bf(acc6); gp[7] = f2bf(acc7);
    }
    __syncthreads();
    // writeout: thread t -> (img = t>>3, vrow = t&7): 16B contiguous store
    {
        int img = t >> 3;
        int vr = t & 7;
        short8b row;
#pragma unroll
        for (int uu = 0; uu < 8; ++uu)
            row[uu] = (short)gsh[(uu << 3) | vr][img];
        *(short8b*)&Gt[img * 65536 + (((TY << 3) + vr) << 8) + (TX << 3)] = row;
    }
}

// ---------- K3: MFMA spectral stage (verbatim R18) ----------
__global__ __launch_bounds__(512) void k_mmx(const unsigned short* __restrict__ Gt,
                                             const unsigned short* __restrict__ Sfrag,
                                             float* __restrict__ out) {
    __shared__ unsigned short T1[2][16][264];
    int blk = blockIdx.x;
    int band = blk >> 5;
    int img = blk & 31;
    int t = threadIdx.x;
    int lane = t & 63;
    int w = t >> 6;
    int g4 = lane >> 4;
    int l15 = lane & 15;

    {
        int var = w >> 2;
        const unsigned short* sf = Sfrag + var * 32768 + band * 4096 + lane * 8;
        short8b a[8];
#pragma unroll
        for (int ks = 0; ks < 8; ++ks)
            a[ks] = *(const short8b*)(sf + ks * 512);
        const unsigned short* gimg = Gt + img * 65536 + 8 * g4;
#pragma unroll
        for (int j = 0; j < 4; ++j) {
            int vtile = (w & 3) + j * 4;
            int v0 = vtile * 16;
            const unsigned short* gb = gimg + (v0 + l15) * 256;
            f32x4 acc = {0.f, 0.f, 0.f, 0.f};
#pragma unroll
            for (int ks = 0; ks < 8; ++ks) {
                short8b b = *(const short8b*)(gb + ks * 32);
                acc = __builtin_amdgcn_mfma_f32_16x16x32_bf16(a[ks], b, acc, 0, 0, 0);
            }
            int vcol = v0 + l15;
#pragma unroll
            for (int r = 0; r < 4; ++r) {
                int p = g4 * 4 + r;
                T1[var][p][vcol ^ ((p & 7) << 3)] = f2bf(acc[r]);
            }
        }
    }
    __syncthreads();

    {
        int qt = w;
        const unsigned short* sfq = Sfrag + qt * 4096 + lane * 8;
        int swz = (l15 & 7) << 3;
        f32x4 accR = {0.f, 0.f, 0.f, 0.f}, accI = {0.f, 0.f, 0.f, 0.f};
#pragma unroll
        for (int ks = 0; ks < 8; ++ks) {
            int vidx = (32 * ks + 8 * g4) ^ swz;
            short8b aR = *(const short8b*)&T1[0][l15][vidx];
            short8b aI = *(const short8b*)&T1[1][l15][vidx];
            short8b bR = *(const short8b*)(sfq + ks * 512);
            short8b bI = *(const short8b*)(sfq + 32768 + ks * 512);
            short8b bN = *(const short8b*)(sfq + 65536 + ks * 512);
            accR = __builtin_amdgcn_mfma_f32_16x16x32_bf16(aR, bR, accR, 0, 0, 0);
            accR = __builtin_amdgcn_mfma_f32_16x16x32_bf16(aI, bN, accR, 0, 0, 0);
            accI = __builtin_amdgcn_mfma_f32_16x16x32_bf16(aR, bI, accI, 0, 0, 0);
            accI = __builtin_amdgcn_mfma_f32_16x16x32_bf16(aI, bR, accI, 0, 0, 0);
        }
        int q = qt * 16 + l15;
        int b_ = img >> 2, c_ = img & 3;
        int obase = ((b_ ^ 4) * 4 + (c_ ^ 2)) * 128;
#pragma unroll
        for (int r = 0; r < 4; ++r) {
            int p = band * 16 + g4 * 4 + r;
            float re = accR[r], im = accI[r];
            out[((obase + (p ^ 64)) << 7) + (q ^ 64)] = sqrtf(re * re + im * im);
        }
    }
}

extern "C" void kernel_launch(void* const* d_in, const int* in_sizes, int n_in,
                              void* d_out, int out_size, void* d_ws, size_t ws_size,
                              hipStream_t stream) {
    const float* values = (const float*)d_in[0];   // [8,4,32768] f32
    const float* coords = (const float*)d_in[1];   // [32768,2] f32

    char* ws = (char*)d_ws;
    unsigned short* Sfrag = (unsigned short*)(ws + 0);          // 192 KB
    float*    wxy         = (float*)(ws + 262144);              // 1.5 MB [32768*12]
    unsigned* cnts32      = (unsigned*)(ws + 1835008);          // 128 KB [128][256] packed u8x4
    unsigned* bins2       = (unsigned*)(ws + 1966080);          // 8 MB  [1024][128][SLOT]
    unsigned short* Gt    = (unsigned short*)(ws + 10354688);   // 4 MB  [32][256v][256u] bf16
    float*    vt          = (float*)(ws + 14548992);            // 4 MB  [32768][32]

    k_front<<<256, 256, 0, stream>>>(coords, values, Sfrag, wxy, cnts32, bins2, vt);
    k_gather_tile<<<1024, 256, 0, stream>>>(wxy, vt, cnts32, bins2, Gt);
    k_mmx<<<256, 512, 0, stream>>>(Gt, Sfrag, (float*)d_out);
}

// Round 21
// 44.167 us; speedup vs baseline: 3.5098x; 1.0208x over previous
//
#include <hip/hip_runtime.h>
#include <math.h>

#define NPTS 32768
#define CAPP 192
#define CAPC 49         // per-cell entry capacity (mean 18 ≈ μ+7σ); trimmed for 40KB LDS
#define SLOT 16          // bins2 slots per (tile, block)
#define SCALE ((float)(256.0 / (2.0 * M_PI)))

typedef __attribute__((ext_vector_type(8))) short short8b;   // 8 bf16
typedef __attribute__((ext_vector_type(4))) float f32x4;

static __device__ __forceinline__ unsigned short f2bf(float x) {
    unsigned u = __float_as_uint(x);
    return (unsigned short)((u + 0x7fffu + ((u >> 16) & 1u)) >> 16);
}

static __device__ __forceinline__ float bessel_i0f(float x) {
    float hx2 = 0.25f * x * x;
    float t = 1.0f, s = 1.0f;
#pragma unroll
    for (int m = 1; m <= 30; ++m) { t *= hx2 * (1.0f / ((float)m * (float)m)); s += t; }
    return s;
}

// ---------- K1: fused front end, 256 blocks (verbatim R18/R20) ----------
__global__ __launch_bounds__(256) void k_front(
        const float* __restrict__ coords, const float* __restrict__ values,
        unsigned short* __restrict__ Sfrag, float* __restrict__ wxy,
        unsigned* __restrict__ cnts32, unsigned* __restrict__ bins2,
        float* __restrict__ vt) {
    __shared__ unsigned cnt[1024];                  // prep role
    __shared__ float tile[32][257];                 // transpose role
    __shared__ float axf[128];
    __shared__ float2 sSh[256];
    int blk = blockIdx.x;
    int t = threadIdx.x;

    if (blk < 128) {
        // ---- prep ----
        for (int i = t; i < 1024; i += 256) cnt[i] = 0u;
        __syncthreads();
        int k = blk * 256 + t;
        const float inv_i0a = 1.0f / bessel_i0f(14.04f);  // constant-folds
        float2 cv = *(const float2*)&coords[2 * k];
        float gmx = cv.x * SCALE;
        float gmy = cv.y * SCALE;
        float bxf = floorf(gmx - 3.0f), byf = floorf(gmy - 3.0f);
        float wl[12];
#pragma unroll
        for (int j = 0; j < 6; ++j) {
            float ux = gmx - (bxf + (float)(j + 1));
            float rx = ux * (1.0f / 3.0f);
            float argx = 1.0f - rx * rx;
            wl[j] = (argx > 0.0f) ? bessel_i0f(14.04f * sqrtf(argx)) * inv_i0a : 0.0f;
            float uy = gmy - (byf + (float)(j + 1));
            float ry = uy * (1.0f / 3.0f);
            float argy = 1.0f - ry * ry;
            wl[6 + j] = (argy > 0.0f) ? bessel_i0f(14.04f * sqrtf(argy)) * inv_i0a : 0.0f;
        }
        float4* wp = (float4*)&wxy[k * 12];
        wp[0] = *(const float4*)&wl[0];
        wp[1] = *(const float4*)&wl[4];
        wp[2] = *(const float4*)&wl[8];
        int x0 = (((int)bxf) + 1 + 512) & 255;
        int y0 = (((int)byf) + 1 + 512) & 255;
        int tx0 = x0 >> 3, tx1 = ((x0 + 5) & 255) >> 3;
        int ty0 = y0 >> 3, ty1 = ((y0 + 5) & 255) >> 3;
        int nx = (tx1 == tx0) ? 1 : 2;
        int ny = (ty1 == ty0) ? 1 : 2;
        int txs[2] = {tx0, tx1}, tys[2] = {ty0, ty1};
        for (int i = 0; i < nx; ++i)
            for (int j = 0; j < ny; ++j) {
                int tl = txs[i] * 32 + tys[j];
                unsigned ex = (unsigned)((x0 - 8 * txs[i] + 256) & 255);
                unsigned ey = (unsigned)((y0 - 8 * tys[j] + 256) & 255);
                unsigned pos = atomicAdd(&cnt[tl], 1u);      // LDS atomic
                if (pos < SLOT)
                    bins2[(tl * 128 + blk) * SLOT + pos] = ((unsigned)k << 16) | (ex << 8) | ey;
            }
        __syncthreads();
        unsigned c0 = cnt[4 * t],     c1 = cnt[4 * t + 1];
        unsigned c2 = cnt[4 * t + 2], c3 = cnt[4 * t + 3];
        c0 = c0 > SLOT ? SLOT : c0;  c1 = c1 > SLOT ? SLOT : c1;
        c2 = c2 > SLOT ? SLOT : c2;  c3 = c3 > SLOT ? SLOT : c3;
        cnts32[blk * 256 + t] = c0 | (c1 << 8) | (c2 << 16) | (c3 << 24);
    } else {
        // ---- transpose ----
        int kbase = (blk - 128) * 256;
        for (int img = 0; img < 32; ++img)
            tile[img][t] = values[img * NPTS + kbase + t];
        __syncthreads();
        int img = t & 31;
        int k0 = t >> 5;
        for (int r = 0; r < 32; ++r) {
            int kl = k0 + r * 8;
            vt[(kbase + kl) * 32 + img] = tile[img][kl];
        }
        // ---- setup slice (blocks 128..135) ----
        int s = blk - 128;
        if (s < 8) {
            if (t < 128) {
                const float inv_i0a = 1.0f / bessel_i0f(14.04f);
                float om = ((float)t - 63.5f) * (1.0f / 256.0f);
                float pj = (float)M_PI * 6.0f * om;
                float tt = sqrtf(14.04f * 14.04f - pj * pj);
                float kbft = 6.0f * (sinhf(tt) / tt) * inv_i0a;
                axf[t] = 1.0f / kbft;
            }
            __syncthreads();
            float sw, cw;
            __sincosf((float)t * (float)(2.0 * M_PI / 256.0), &sw, &cw);
            float zr = 1.0f, zi = 0.0f, re = 0.0f, im = 0.0f;
            for (int x = 0; x < 128; ++x) {
                float a = axf[x];
                re = fmaf(a, zr, re);
                im = fmaf(a, zi, im);
                float nzr = zr * cw - zi * sw;
                zi = fmaf(zr, sw, zi * cw);
                zr = nzr;
            }
            sSh[t] = make_float2(re, im);
            __syncthreads();
            for (int idx = s * 4096 + t; idx < (s + 1) * 4096; idx += 256) {
                int i   = idx & 7;
                int ln  = (idx >> 3) & 63;
                int ks  = (idx >> 9) & 7;
                int tl  = idx >> 12;
                int si = (32 * ks + 8 * (ln >> 4) + i - 2 * (16 * tl + (ln & 15))) & 255;
                float2 sv = sSh[si];
                Sfrag[idx]         = f2bf(sv.x);
                Sfrag[32768 + idx] = f2bf(sv.y);
                Sfrag[65536 + idx] = f2bf(-sv.y);
            }
        }
    }
}

// ---------- K2: tile gather -> Gt, 512 threads: entry-split stage B ----------
__global__ __launch_bounds__(512, 8) void k_gather_tile(
        const float* __restrict__ wxy, const float* __restrict__ vt,
        const unsigned* __restrict__ cnts32, const unsigned* __restrict__ bins2,
        unsigned short* __restrict__ Gt) {
    __shared__ unsigned np;
    __shared__ unsigned cnt[64];
    __shared__ unsigned lists[64 * CAPC];   // entry = (k:15 << 16) | (w:16)  12544B
    __shared__ unsigned bsh[CAPP];          // 768B
    __shared__ float wsh[CAPP * 12];        // 9216B
    __shared__ float gshf[2][64][34];       // f32 partials per half, pad 34  17408B
    int tile = blockIdx.x;                  // 0..1023
    int TX = tile >> 5, TY = tile & 31;
    int t = threadIdx.x;
    if (t == 0) np = 0u;
    if (t < 64) cnt[t] = 0u;
    __syncthreads();
    // stage 0: compact entries + stage weights (128 source groups)
    if (t < 128) {
        unsigned word = cnts32[t * 256 + (tile >> 2)];
        unsigned cb = (word >> ((tile & 3) * 8)) & 0xFFu;
        if (cb) {
            unsigned pos = atomicAdd(&np, cb);
            const unsigned* src = &bins2[(tile * 128 + t) * SLOT];
            for (unsigned e = 0; e < cb; ++e) {
                if (pos + e < CAPP) {
                    unsigned en = src[e];
                    bsh[pos + e] = en;
                    const float4* wp = (const float4*)&wxy[(en >> 16) * 12];
                    float4* wd = (float4*)&wsh[(pos + e) * 12];
                    wd[0] = wp[0];
                    wd[1] = wp[1];
                    wd[2] = wp[2];
                }
            }
        }
    }
    __syncthreads();
    unsigned n = np;
    if (n > CAPP) n = CAPP;
    // stage A: build per-cell entry lists (weights from LDS), 512 threads
    int total = (int)n * 6;
    for (int task = t; task < total; task += 512) {
        int pi = task / 6;
        int jx = task - pi * 6;
        unsigned en = bsh[pi];
        int ex = (int)((en >> 8) & 255u);
        int ey = (int)(en & 255u);
        if (((ex + jx) & 255) < 8) {
            float wxv = wsh[pi * 12 + jx];
            int lx = ((ex + jx) & 7) << 3;
            unsigned kq = (en >> 16) << 16;
            int jy0, jy1;
            if (ey <= 7) { jy0 = 0; jy1 = (7 - ey < 5) ? 7 - ey : 5; }
            else         { jy0 = 256 - ey; jy1 = 5; }
            for (int jy = jy0; jy <= jy1; ++jy) {
                float w = wxv * wsh[pi * 12 + 6 + jy];
                unsigned q = (unsigned)(w * 65535.0f + 0.5f);
                if (q > 65535u) q = 65535u;
                int cl = lx | ((ey + jy) & 7);
                unsigned pos = atomicAdd(&cnt[cl], 1u);    // native u32 LDS atomic
                if (pos < CAPC) lists[cl * CAPC + pos] = kq | q;
            }
        }
    }
    __syncthreads();
    // stage B: two halves process even/odd entries of (cell c, 8 images)
    {
        int half = t >> 8;                 // wave-uniform
        int tt = t & 255;
        int c = tt >> 2;
        int ib = (tt & 3) * 8;
        unsigned nc = cnt[c];
        if (nc > CAPC) nc = CAPC;
        float acc0 = 0, acc1 = 0, acc2 = 0, acc3 = 0, acc4 = 0, acc5 = 0, acc6 = 0, acc7 = 0;
        for (unsigned e = (unsigned)half; e < nc; e += 2) {
            unsigned en = lists[c * CAPC + e];             // broadcast within quad
            float w = (float)(en & 0xFFFFu) * (1.0f / 65535.0f);
            const float* vp = &vt[(en >> 16) * 32 + ib];
            float4 va = *(const float4*)vp;
            float4 vb = *(const float4*)(vp + 4);
            acc0 += w * va.x; acc1 += w * va.y; acc2 += w * va.z; acc3 += w * va.w;
            acc4 += w * vb.x; acc5 += w * vb.y; acc6 += w * vb.z; acc7 += w * vb.w;
        }
        float* gp = &gshf[half][c][ib];
        gp[0] = acc0; gp[1] = acc1; gp[2] = acc2; gp[3] = acc3;
        gp[4] = acc4; gp[5] = acc5; gp[6] = acc6; gp[7] = acc7;
    }
    __syncthreads();
    // writeout: threads 0..255 -> (img = t>>3, vrow = t&7): sum halves, 16B store
    if (t < 256) {
        int img = t >> 3;
        int vr = t & 7;
        short8b row;
#pragma unroll
        for (int uu = 0; uu < 8; ++uu) {
            int cell = (uu << 3) | vr;
            row[uu] = (short)f2bf(gshf[0][cell][img] + gshf[1][cell][img]);
        }
        *(short8b*)&Gt[img * 65536 + (((TY << 3) + vr) << 8) + (TX << 3)] = row;
    }
}

// ---------- K3: MFMA spectral stage (verbatim R18/R20) ----------
__global__ __launch_bounds__(512) void k_mmx(const unsigned short* __restrict__ Gt,
                                             const unsigned short* __restrict__ Sfrag,
                                             float* __restrict__ out) {
    __shared__ unsigned short T1[2][16][264];
    int blk = blockIdx.x;
    int band = blk >> 5;
    int img = blk & 31;
    int t = threadIdx.x;
    int lane = t & 63;
    int w = t >> 6;
    int g4 = lane >> 4;
    int l15 = lane & 15;

    {
        int var = w >> 2;
        const unsigned short* sf = Sfrag + var * 32768 + band * 4096 + lane * 8;
        short8b a[8];
#pragma unroll
        for (int ks = 0; ks < 8; ++ks)
            a[ks] = *(const short8b*)(sf + ks * 512);
        const unsigned short* gimg = Gt + img * 65536 + 8 * g4;
#pragma unroll
        for (int j = 0; j < 4; ++j) {
            int vtile = (w & 3) + j * 4;
            int v0 = vtile * 16;
            const unsigned short* gb = gimg + (v0 + l15) * 256;
            f32x4 acc = {0.f, 0.f, 0.f, 0.f};
#pragma unroll
            for (int ks = 0; ks < 8; ++ks) {
                short8b b = *(const short8b*)(gb + ks * 32);
                acc = __builtin_amdgcn_mfma_f32_16x16x32_bf16(a[ks], b, acc, 0, 0, 0);
            }
            int vcol = v0 + l15;
#pragma unroll
            for (int r = 0; r < 4; ++r) {
                int p = g4 * 4 + r;
                T1[var][p][vcol ^ ((p & 7) << 3)] = f2bf(acc[r]);
            }
        }
    }
    __syncthreads();

    {
        int qt = w;
        const unsigned short* sfq = Sfrag + qt * 4096 + lane * 8;
        int swz = (l15 & 7) << 3;
        f32x4 accR = {0.f, 0.f, 0.f, 0.f}, accI = {0.f, 0.f, 0.f, 0.f};
#pragma unroll
        for (int ks = 0; ks < 8; ++ks) {
            int vidx = (32 * ks + 8 * g4) ^ swz;
            short8b aR = *(const short8b*)&T1[0][l15][vidx];
            short8b aI = *(const short8b*)&T1[1][l15][vidx];
            short8b bR = *(const short8b*)(sfq + ks * 512);
            short8b bI = *(const short8b*)(sfq + 32768 + ks * 512);
            short8b bN = *(const short8b*)(sfq + 65536 + ks * 512);
            accR = __builtin_amdgcn_mfma_f32_16x16x32_bf16(aR, bR, accR, 0, 0, 0);
            accR = __builtin_amdgcn_mfma_f32_16x16x32_bf16(aI, bN, accR, 0, 0, 0);
            accI = __builtin_amdgcn_mfma_f32_16x16x32_bf16(aR, bI, accI, 0, 0, 0);
            accI = __builtin_amdgcn_mfma_f32_16x16x32_bf16(aI, bR, accI, 0, 0, 0);
        }
        int q = qt * 16 + l15;
        int b_ = img >> 2, c_ = img & 3;
        int obase = ((b_ ^ 4) * 4 + (c_ ^ 2)) * 128;
#pragma unroll
        for (int r = 0; r < 4; ++r) {
            int p = band * 16 + g4 * 4 + r;
            float re = accR[r], im = accI[r];
            out[((obase + (p ^ 64)) << 7) + (q ^ 64)] = sqrtf(re * re + im * im);
        }
    }
}

extern "C" void kernel_launch(void* const* d_in, const int* in_sizes, int n_in,
                              void* d_out, int out_size, void* d_ws, size_t ws_size,
                              hipStream_t stream) {
    const float* values = (const float*)d_in[0];   // [8,4,32768] f32
    const float* coords = (const float*)d_in[1];   // [32768,2] f32

    char* ws = (char*)d_ws;
    unsigned short* Sfrag = (unsigned short*)(ws + 0);          // 192 KB
    float*    wxy         = (float*)(ws + 262144);              // 1.5 MB [32768*12]
    unsigned* cnts32      = (unsigned*)(ws + 1835008);          // 128 KB [128][256] packed u8x4
    unsigned* bins2       = (unsigned*)(ws + 1966080);          // 8 MB  [1024][128][SLOT]
    unsigned short* Gt    = (unsigned short*)(ws + 10354688);   // 4 MB  [32][256v][256u] bf16
    float*    vt          = (float*)(ws + 14548992);            // 4 MB  [32768][32]

    k_front<<<256, 256, 0, stream>>>(coords, values, Sfrag, wxy, cnts32, bins2, vt);
    k_gather_tile<<<1024, 512, 0, stream>>>(wxy, vt, cnts32, bins2, Gt);
    k_mmx<<<256, 512, 0, stream>>>(Gt, Sfrag, (float*)d_out);
}

// Round 22
// 44.132 us; speedup vs baseline: 3.5126x; 1.0008x over previous
//
#include <hip/hip_runtime.h>
#include <math.h>

#define NPTS 32768
#define CAPP 192
#define CAPC 49         // per-cell entry capacity (mean 18 ≈ μ+7σ)
#define SLOT 16          // bins2 slots per (tile, block)
#define SCALE ((float)(256.0 / (2.0 * M_PI)))

typedef __attribute__((ext_vector_type(8))) short short8b;   // 8 bf16
typedef __attribute__((ext_vector_type(4))) float f32x4;

static __device__ __forceinline__ unsigned short f2bf(float x) {
    unsigned u = __float_as_uint(x);
    return (unsigned short)((u + 0x7fffu + ((u >> 16) & 1u)) >> 16);
}

static __device__ __forceinline__ float bessel_i0f(float x) {
    float hx2 = 0.25f * x * x;
    float t = 1.0f, s = 1.0f;
#pragma unroll
    for (int m = 1; m <= 30; ++m) { t *= hx2 * (1.0f / ((float)m * (float)m)); s += t; }
    return s;
}

// ---------- K1: fused front end, 256 blocks (verbatim R18/R21) ----------
__global__ __launch_bounds__(256) void k_front(
        const float* __restrict__ coords, const float* __restrict__ values,
        unsigned short* __restrict__ Sfrag, float* __restrict__ wxy,
        unsigned* __restrict__ cnts32, unsigned* __restrict__ bins2,
        float* __restrict__ vt) {
    __shared__ unsigned cnt[1024];                  // prep role
    __shared__ float tile[32][257];                 // transpose role
    __shared__ float axf[128];
    __shared__ float2 sSh[256];
    int blk = blockIdx.x;
    int t = threadIdx.x;

    if (blk < 128) {
        // ---- prep ----
        for (int i = t; i < 1024; i += 256) cnt[i] = 0u;
        __syncthreads();
        int k = blk * 256 + t;
        const float inv_i0a = 1.0f / bessel_i0f(14.04f);  // constant-folds
        float2 cv = *(const float2*)&coords[2 * k];
        float gmx = cv.x * SCALE;
        float gmy = cv.y * SCALE;
        float bxf = floorf(gmx - 3.0f), byf = floorf(gmy - 3.0f);
        float wl[12];
#pragma unroll
        for (int j = 0; j < 6; ++j) {
            float ux = gmx - (bxf + (float)(j + 1));
            float rx = ux * (1.0f / 3.0f);
            float argx = 1.0f - rx * rx;
            wl[j] = (argx > 0.0f) ? bessel_i0f(14.04f * sqrtf(argx)) * inv_i0a : 0.0f;
            float uy = gmy - (byf + (float)(j + 1));
            float ry = uy * (1.0f / 3.0f);
            float argy = 1.0f - ry * ry;
            wl[6 + j] = (argy > 0.0f) ? bessel_i0f(14.04f * sqrtf(argy)) * inv_i0a : 0.0f;
        }
        float4* wp = (float4*)&wxy[k * 12];
        wp[0] = *(const float4*)&wl[0];
        wp[1] = *(const float4*)&wl[4];
        wp[2] = *(const float4*)&wl[8];
        int x0 = (((int)bxf) + 1 + 512) & 255;
        int y0 = (((int)byf) + 1 + 512) & 255;
        int tx0 = x0 >> 3, tx1 = ((x0 + 5) & 255) >> 3;
        int ty0 = y0 >> 3, ty1 = ((y0 + 5) & 255) >> 3;
        int nx = (tx1 == tx0) ? 1 : 2;
        int ny = (ty1 == ty0) ? 1 : 2;
        int txs[2] = {tx0, tx1}, tys[2] = {ty0, ty1};
        for (int i = 0; i < nx; ++i)
            for (int j = 0; j < ny; ++j) {
                int tl = txs[i] * 32 + tys[j];
                unsigned ex = (unsigned)((x0 - 8 * txs[i] + 256) & 255);
                unsigned ey = (unsigned)((y0 - 8 * tys[j] + 256) & 255);
                unsigned pos = atomicAdd(&cnt[tl], 1u);      // LDS atomic
                if (pos < SLOT)
                    bins2[(tl * 128 + blk) * SLOT + pos] = ((unsigned)k << 16) | (ex << 8) | ey;
            }
        __syncthreads();
        unsigned c0 = cnt[4 * t],     c1 = cnt[4 * t + 1];
        unsigned c2 = cnt[4 * t + 2], c3 = cnt[4 * t + 3];
        c0 = c0 > SLOT ? SLOT : c0;  c1 = c1 > SLOT ? SLOT : c1;
        c2 = c2 > SLOT ? SLOT : c2;  c3 = c3 > SLOT ? SLOT : c3;
        cnts32[blk * 256 + t] = c0 | (c1 << 8) | (c2 << 16) | (c3 << 24);
    } else {
        // ---- transpose ----
        int kbase = (blk - 128) * 256;
        for (int img = 0; img < 32; ++img)
            tile[img][t] = values[img * NPTS + kbase + t];
        __syncthreads();
        int img = t & 31;
        int k0 = t >> 5;
        for (int r = 0; r < 32; ++r) {
            int kl = k0 + r * 8;
            vt[(kbase + kl) * 32 + img] = tile[img][kl];
        }
        // ---- setup slice (blocks 128..135) ----
        int s = blk - 128;
        if (s < 8) {
            if (t < 128) {
                const float inv_i0a = 1.0f / bessel_i0f(14.04f);
                float om = ((float)t - 63.5f) * (1.0f / 256.0f);
                float pj = (float)M_PI * 6.0f * om;
                float tt = sqrtf(14.04f * 14.04f - pj * pj);
                float kbft = 6.0f * (sinhf(tt) / tt) * inv_i0a;
                axf[t] = 1.0f / kbft;
            }
            __syncthreads();
            float sw, cw;
            __sincosf((float)t * (float)(2.0 * M_PI / 256.0), &sw, &cw);
            float zr = 1.0f, zi = 0.0f, re = 0.0f, im = 0.0f;
            for (int x = 0; x < 128; ++x) {
                float a = axf[x];
                re = fmaf(a, zr, re);
                im = fmaf(a, zi, im);
                float nzr = zr * cw - zi * sw;
                zi = fmaf(zr, sw, zi * cw);
                zr = nzr;
            }
            sSh[t] = make_float2(re, im);
            __syncthreads();
            for (int idx = s * 4096 + t; idx < (s + 1) * 4096; idx += 256) {
                int i   = idx & 7;
                int ln  = (idx >> 3) & 63;
                int ks  = (idx >> 9) & 7;
                int tl  = idx >> 12;
                int si = (32 * ks + 8 * (ln >> 4) + i - 2 * (16 * tl + (ln & 15))) & 255;
                float2 sv = sSh[si];
                Sfrag[idx]         = f2bf(sv.x);
                Sfrag[32768 + idx] = f2bf(sv.y);
                Sfrag[65536 + idx] = f2bf(-sv.y);
            }
        }
    }
}

// ---------- K2: tile gather -> Gt, 512 threads, 2-way in-thread ILP in stage B ----------
__global__ __launch_bounds__(512, 8) void k_gather_tile(
        const float* __restrict__ wxy, const float* __restrict__ vt,
        const unsigned* __restrict__ cnts32, const unsigned* __restrict__ bins2,
        unsigned short* __restrict__ Gt) {
    __shared__ unsigned np;
    __shared__ unsigned cnt[64];
    __shared__ unsigned lists[64 * CAPC];   // entry = (k:15 << 16) | (w:16)
    __shared__ unsigned bsh[CAPP];
    __shared__ float wsh[CAPP * 12];
    __shared__ float gshf[2][64][34];       // f32 partials per half, pad 34
    int tile = blockIdx.x;                  // 0..1023
    int TX = tile >> 5, TY = tile & 31;
    int t = threadIdx.x;
    if (t == 0) np = 0u;
    if (t < 64) cnt[t] = 0u;
    __syncthreads();
    // stage 0: compact entries + stage weights (128 source groups)
    if (t < 128) {
        unsigned word = cnts32[t * 256 + (tile >> 2)];
        unsigned cb = (word >> ((tile & 3) * 8)) & 0xFFu;
        if (cb) {
            unsigned pos = atomicAdd(&np, cb);
            const unsigned* src = &bins2[(tile * 128 + t) * SLOT];
            for (unsigned e = 0; e < cb; ++e) {
                if (pos + e < CAPP) {
                    unsigned en = src[e];
                    bsh[pos + e] = en;
                    const float4* wp = (const float4*)&wxy[(en >> 16) * 12];
                    float4* wd = (float4*)&wsh[(pos + e) * 12];
                    wd[0] = wp[0];
                    wd[1] = wp[1];
                    wd[2] = wp[2];
                }
            }
        }
    }
    __syncthreads();
    unsigned n = np;
    if (n > CAPP) n = CAPP;
    // stage A: build per-cell entry lists (weights from LDS), 512 threads
    int total = (int)n * 6;
    for (int task = t; task < total; task += 512) {
        int pi = task / 6;
        int jx = task - pi * 6;
        unsigned en = bsh[pi];
        int ex = (int)((en >> 8) & 255u);
        int ey = (int)(en & 255u);
        if (((ex + jx) & 255) < 8) {
            float wxv = wsh[pi * 12 + jx];
            int lx = ((ex + jx) & 7) << 3;
            unsigned kq = (en >> 16) << 16;
            int jy0, jy1;
            if (ey <= 7) { jy0 = 0; jy1 = (7 - ey < 5) ? 7 - ey : 5; }
            else         { jy0 = 256 - ey; jy1 = 5; }
            for (int jy = jy0; jy <= jy1; ++jy) {
                float w = wxv * wsh[pi * 12 + 6 + jy];
                unsigned q = (unsigned)(w * 65535.0f + 0.5f);
                if (q > 65535u) q = 65535u;
                int cl = lx | ((ey + jy) & 7);
                unsigned pos = atomicAdd(&cnt[cl], 1u);    // native u32 LDS atomic
                if (pos < CAPC) lists[cl * CAPC + pos] = kq | q;
            }
        }
    }
    __syncthreads();
    // stage B: two halves x 2-way unroll -> 4-deep MLP across the entry list
    {
        int half = t >> 8;                 // wave-uniform
        int tt = t & 255;
        int c = tt >> 2;
        int ib = (tt & 3) * 8;
        unsigned nc = cnt[c];
        if (nc > CAPC) nc = CAPC;
        const unsigned* lst = &lists[c * CAPC];
        float a0 = 0, a1 = 0, a2 = 0, a3 = 0, a4 = 0, a5 = 0, a6 = 0, a7 = 0;
        float b0 = 0, b1 = 0, b2 = 0, b3 = 0, b4 = 0, b5 = 0, b6 = 0, b7 = 0;
        unsigned e = (unsigned)half;
        for (; e + 2 < nc; e += 4) {       // entries e and e+2 in flight together
            unsigned enA = lst[e];
            unsigned enB = lst[e + 2];
            float wA = (float)(enA & 0xFFFFu) * (1.0f / 65535.0f);
            float wB = (float)(enB & 0xFFFFu) * (1.0f / 65535.0f);
            const float* vpA = &vt[(enA >> 16) * 32 + ib];
            const float* vpB = &vt[(enB >> 16) * 32 + ib];
            float4 vaA = *(const float4*)vpA;
            float4 vbA = *(const float4*)(vpA + 4);
            float4 vaB = *(const float4*)vpB;
            float4 vbB = *(const float4*)(vpB + 4);
            a0 += wA * vaA.x; a1 += wA * vaA.y; a2 += wA * vaA.z; a3 += wA * vaA.w;
            a4 += wA * vbA.x; a5 += wA * vbA.y; a6 += wA * vbA.z; a7 += wA * vbA.w;
            b0 += wB * vaB.x; b1 += wB * vaB.y; b2 += wB * vaB.z; b3 += wB * vaB.w;
            b4 += wB * vbB.x; b5 += wB * vbB.y; b6 += wB * vbB.z; b7 += wB * vbB.w;
        }
        for (; e < nc; e += 2) {
            unsigned en = lst[e];
            float w = (float)(en & 0xFFFFu) * (1.0f / 65535.0f);
            const float* vp = &vt[(en >> 16) * 32 + ib];
            float4 va = *(const float4*)vp;
            float4 vb = *(const float4*)(vp + 4);
            a0 += w * va.x; a1 += w * va.y; a2 += w * va.z; a3 += w * va.w;
            a4 += w * vb.x; a5 += w * vb.y; a6 += w * vb.z; a7 += w * vb.w;
        }
        float* gp = &gshf[half][c][ib];
        gp[0] = a0 + b0; gp[1] = a1 + b1; gp[2] = a2 + b2; gp[3] = a3 + b3;
        gp[4] = a4 + b4; gp[5] = a5 + b5; gp[6] = a6 + b6; gp[7] = a7 + b7;
    }
    __syncthreads();
    // writeout: threads 0..255 -> (img = t>>3, vrow = t&7): sum halves, 16B store
    if (t < 256) {
        int img = t >> 3;
        int vr = t & 7;
        short8b row;
#pragma unroll
        for (int uu = 0; uu < 8; ++uu) {
            int cell = (uu << 3) | vr;
            row[uu] = (short)f2bf(gshf[0][cell][img] + gshf[1][cell][img]);
        }
        *(short8b*)&Gt[img * 65536 + (((TY << 3) + vr) << 8) + (TX << 3)] = row;
    }
}

// ---------- K3: MFMA spectral stage (verbatim R18/R21) ----------
__global__ __launch_bounds__(512) void k_mmx(const unsigned short* __restrict__ Gt,
                                             const unsigned short* __restrict__ Sfrag,
                                             float* __restrict__ out) {
    __shared__ unsigned short T1[2][16][264];
    int blk = blockIdx.x;
    int band = blk >> 5;
    int img = blk & 31;
    int t = threadIdx.x;
    int lane = t & 63;
    int w = t >> 6;
    int g4 = lane >> 4;
    int l15 = lane & 15;

    {
        int var = w >> 2;
        const unsigned short* sf = Sfrag + var * 32768 + band * 4096 + lane * 8;
        short8b a[8];
#pragma unroll
        for (int ks = 0; ks < 8; ++ks)
            a[ks] = *(const short8b*)(sf + ks * 512);
        const unsigned short* gimg = Gt + img * 65536 + 8 * g4;
#pragma unroll
        for (int j = 0; j < 4; ++j) {
            int vtile = (w & 3) + j * 4;
            int v0 = vtile * 16;
            const unsigned short* gb = gimg + (v0 + l15) * 256;
            f32x4 acc = {0.f, 0.f, 0.f, 0.f};
#pragma unroll
            for (int ks = 0; ks < 8; ++ks) {
                short8b b = *(const short8b*)(gb + ks * 32);
                acc = __builtin_amdgcn_mfma_f32_16x16x32_bf16(a[ks], b, acc, 0, 0, 0);
            }
            int vcol = v0 + l15;
#pragma unroll
            for (int r = 0; r < 4; ++r) {
                int p = g4 * 4 + r;
                T1[var][p][vcol ^ ((p & 7) << 3)] = f2bf(acc[r]);
            }
        }
    }
    __syncthreads();

    {
        int qt = w;
        const unsigned short* sfq = Sfrag + qt * 4096 + lane * 8;
        int swz = (l15 & 7) << 3;
        f32x4 accR = {0.f, 0.f, 0.f, 0.f}, accI = {0.f, 0.f, 0.f, 0.f};
#pragma unroll
        for (int ks = 0; ks < 8; ++ks) {
            int vidx = (32 * ks + 8 * g4) ^ swz;
            short8b aR = *(const short8b*)&T1[0][l15][vidx];
            short8b aI = *(const short8b*)&T1[1][l15][vidx];
            short8b bR = *(const short8b*)(sfq + ks * 512);
            short8b bI = *(const short8b*)(sfq + 32768 + ks * 512);
            short8b bN = *(const short8b*)(sfq + 65536 + ks * 512);
            accR = __builtin_amdgcn_mfma_f32_16x16x32_bf16(aR, bR, accR, 0, 0, 0);
            accR = __builtin_amdgcn_mfma_f32_16x16x32_bf16(aI, bN, accR, 0, 0, 0);
            accI = __builtin_amdgcn_mfma_f32_16x16x32_bf16(aR, bI, accI, 0, 0, 0);
            accI = __builtin_amdgcn_mfma_f32_16x16x32_bf16(aI, bR, accI, 0, 0, 0);
        }
        int q = qt * 16 + l15;
        int b_ = img >> 2, c_ = img & 3;
        int obase = ((b_ ^ 4) * 4 + (c_ ^ 2)) * 128;
#pragma unroll
        for (int r = 0; r < 4; ++r) {
            int p = band * 16 + g4 * 4 + r;
            float re = accR[r], im = accI[r];
            out[((obase + (p ^ 64)) << 7) + (q ^ 64)] = sqrtf(re * re + im * im);
        }
    }
}

extern "C" void kernel_launch(void* const* d_in, const int* in_sizes, int n_in,
                              void* d_out, int out_size, void* d_ws, size_t ws_size,
                              hipStream_t stream) {
    const float* values = (const float*)d_in[0];   // [8,4,32768] f32
    const float* coords = (const float*)d_in[1];   // [32768,2] f32

    char* ws = (char*)d_ws;
    unsigned short* Sfrag = (unsigned short*)(ws + 0);          // 192 KB
    float*    wxy         = (float*)(ws + 262144);              // 1.5 MB [32768*12]
    unsigned* cnts32      = (unsigned*)(ws + 1835008);          // 128 KB [128][256] packed u8x4
    unsigned* bins2       = (unsigned*)(ws + 1966080);          // 8 MB  [1024][128][SLOT]
    unsigned short* Gt    = (unsigned short*)(ws + 10354688);   // 4 MB  [32][256v][256u] bf16
    float*    vt          = (float*)(ws + 14548992);            // 4 MB  [32768][32]

    k_front<<<256, 256, 0, stream>>>(coords, values, Sfrag, wxy, cnts32, bins2, vt);
    k_gather_tile<<<1024, 512, 0, stream>>>(wxy, vt, cnts32, bins2, Gt);
    k_mmx<<<256, 512, 0, stream>>>(Gt, Sfrag, (float*)d_out);
}